// Round 4
// baseline (190.016 us; speedup 1.0000x reference)
//
#include <hip/hip_runtime.h>
#include <hip/hip_bf16.h>

// KANLayer: out = x @ Wb^T + silu(x) @ sum_g(Ws)^T
// One packed bf16 GEMM, K=2048: A'=[x|silu(x)], W'=[Wb|sum_g Ws], out=A'@W'^T.
// R4: (a) slot-major LDS layout -> conflict-free b128 fragment reads
//     (b) double-buffered LDS, 1 barrier/iter, prefetch drained a full
//         compute-phase later (hides global latency)
//     (c) back to 128x128 tile (best staging-bytes per MFMA).

#define BATCH 8192
#define IN_F 1024
#define OUT_F 1024
#define KP 2048

typedef unsigned short ushort_t;
typedef __attribute__((ext_vector_type(8))) short short8;
typedef __attribute__((ext_vector_type(4))) float f32x4;

__device__ __forceinline__ ushort_t f2bf(float f) {
  union { float f; unsigned int u; } v;
  v.f = f;
  unsigned int u = v.u;
  u += 0x7fffu + ((u >> 16) & 1u);  // RNE
  return (ushort_t)(u >> 16);
}

__device__ __forceinline__ void async16(const ushort_t* g, ushort_t* l) {
  __builtin_amdgcn_global_load_lds(
      (const __attribute__((address_space(1))) void*)g,
      (__attribute__((address_space(3))) void*)l, 16, 0, 0);
}

// ---------------- merged prep (unchanged: ~traffic floor) -----------
#define PREP_A_BLOCKS 4096
#define PREP_S_BLOCKS 1024
#define PREP_B_BLOCKS 1024
#define PREP_BLOCKS (PREP_A_BLOCKS + PREP_S_BLOCKS + PREP_B_BLOCKS)

__global__ __launch_bounds__(256) void prep_all(
    const float* __restrict__ x, const float* __restrict__ Wb,
    const float* __restrict__ Ws, ushort_t* __restrict__ Apack,
    ushort_t* __restrict__ Wpack) {
  const int blk = blockIdx.x;
  const int t = threadIdx.x;

  if (blk < PREP_A_BLOCKS) {
    const int idx = blk * 256 + t;
    const int b = idx >> 7;
    const int i = (idx & 127) << 3;
    const float4 x0 = *(const float4*)(x + ((size_t)b << 10) + i);
    const float4 x1 = *(const float4*)(x + ((size_t)b << 10) + i + 4);
    float xv[8] = {x0.x, x0.y, x0.z, x0.w, x1.x, x1.y, x1.z, x1.w};
    ushort_t vb[8], vs[8];
#pragma unroll
    for (int j = 0; j < 8; ++j) {
      vb[j] = f2bf(xv[j]);
      vs[j] = f2bf(xv[j] / (1.0f + __expf(-xv[j])));
    }
    ushort_t* row = Apack + ((size_t)b << 11);
    *(short8*)(row + i) = *(short8*)vb;
    *(short8*)(row + IN_F + i) = *(short8*)vs;
  } else if (blk < PREP_A_BLOCKS + PREP_S_BLOCKS) {
    const int idx = (blk - PREP_A_BLOCKS) * 256 + t;
    const int o = idx >> 8;
    const int i0 = (idx & 255) << 2;
    ushort_t vs[4];
#pragma unroll
    for (int j = 0; j < 4; ++j) {
      const float4* p = (const float4*)(Ws + ((((size_t)o << 10) + i0 + j) << 3));
      const float4 a = p[0];
      const float4 b = p[1];
      vs[j] = f2bf(((a.x + a.y) + (a.z + a.w)) + ((b.x + b.y) + (b.z + b.w)));
    }
    *(ushort4*)(Wpack + ((size_t)o << 11) + IN_F + i0) = *(ushort4*)vs;
  } else {
    const int idx = (blk - PREP_A_BLOCKS - PREP_S_BLOCKS) * 256 + t;
    const int o = idx >> 8;
    const int c = (idx & 255) << 2;
    const float4 w = *(const float4*)(Wb + ((size_t)o << 10) + c);
    ushort4 v;
    v.x = f2bf(w.x); v.y = f2bf(w.y); v.z = f2bf(w.z); v.w = f2bf(w.w);
    *(ushort4*)(Wpack + ((size_t)o << 11) + c) = v;
  }
}

// ---------------- GEMM ----------------
// C[M][N] = A[M][K] @ W[N][K]^T. 128x128 tile, BK=32, 256 thr = 4 waves,
// wave tile 64x64 (4x4 frags of 16x16x32). Grid (8,64) = 512 blocks.
//
// LDS geometry (slot-major): tile = [kslot 0..3][row 0..127][8 bf16 = 16B].
//   elem addr = kslot*1024 + row*8. Fragment read: 16 consecutive lanes read
//   consecutive rows -> 16B stride -> 2 lanes/bank -> conflict-free.
//   Staging round r (r=0,1): thread t fetches global (row=t&127,
//   kslot=(t>>7)+2r); forced LDS dest base + t*16B == kslot*2048B + row*16B. OK.
// Double buffer: prefetch k+1 issued right after the barrier, drained at the
//   NEXT barrier -> full compute phase of in-flight time.
__global__ __launch_bounds__(256) void gemm_packed(
    const ushort_t* __restrict__ A,  // [BATCH][KP]
    const ushort_t* __restrict__ W,  // [OUT_F][KP]
    float* __restrict__ C) {         // [BATCH][OUT_F]
  __shared__ ushort_t As[2 * 4096];  // 16 KB (2 buffers x 8 KB)
  __shared__ ushort_t Bs[2 * 4096];

  const int t = threadIdx.x;
  const int flat = blockIdx.y * 8 + blockIdx.x;
  const int xcd = flat & 7;
  const int local = flat >> 3;           // 0..63
  const int nt = local >> 3;             // N-tile 0..7
  const int mt = xcd * 8 + (local & 7);  // M-tile 0..63

  const int lane = t & 63;
  const int wave = t >> 6;
  const int wr = wave >> 1;
  const int wc = wave & 1;

  // staging source: row = t&127, kslot0 = t>>7 (round r adds 2 slots = 16 elems)
  const int srow = t & 127;
  const int sslot = t >> 7;
  const ushort_t* a_g = A + ((size_t)(mt * 128 + srow)) * KP + sslot * 8;
  const ushort_t* b_g = W + ((size_t)(nt * 128 + srow)) * KP + sslot * 8;
  const int t8 = t * 8;

  f32x4 acc[4][4];
#pragma unroll
  for (int mi = 0; mi < 4; ++mi)
#pragma unroll
    for (int ni = 0; ni < 4; ++ni) acc[mi][ni] = (f32x4){0.f, 0.f, 0.f, 0.f};

  // fragment read offsets (within a buffer): kslot = lane>>4, row base below
  const int arow = wr * 64 + (lane & 15);
  const int brow = wc * 64 + (lane & 15);
  const int rk = (lane >> 4) * 1024;

  // prologue: stage tile 0 into buffer 0
  async16(a_g, As + t8);
  async16(a_g + 16, As + 2048 + t8);
  async16(b_g, Bs + t8);
  async16(b_g + 16, Bs + 2048 + t8);

  int p = 0;
  for (int k0 = 0; k0 < KP; k0 += 32, p ^= 1) {
    __syncthreads();  // drains prefetch (vmcnt0) + guards buffer reuse
    if (k0 + 32 < KP) {
      const int q = p ^ 1;
      async16(a_g + k0 + 32, As + q * 4096 + t8);
      async16(a_g + k0 + 48, As + q * 4096 + 2048 + t8);
      async16(b_g + k0 + 32, Bs + q * 4096 + t8);
      async16(b_g + k0 + 48, Bs + q * 4096 + 2048 + t8);
    }

    const ushort_t* ab = As + p * 4096 + rk;
    const ushort_t* bb = Bs + p * 4096 + rk;
    short8 af[4], bfr[4];
#pragma unroll
    for (int mi = 0; mi < 4; ++mi)
      af[mi] = *(const short8*)(ab + (arow + mi * 16) * 8);
#pragma unroll
    for (int ni = 0; ni < 4; ++ni)
      bfr[ni] = *(const short8*)(bb + (brow + ni * 16) * 8);

#pragma unroll
    for (int mi = 0; mi < 4; ++mi)
#pragma unroll
      for (int ni = 0; ni < 4; ++ni)
        acc[mi][ni] = __builtin_amdgcn_mfma_f32_16x16x32_bf16(af[mi], bfr[ni], acc[mi][ni], 0, 0, 0);
  }

  const int col0 = nt * 128 + wc * 64 + (lane & 15);
  const int row0 = mt * 128 + wr * 64 + ((lane >> 4) << 2);
#pragma unroll
  for (int mi = 0; mi < 4; ++mi)
#pragma unroll
    for (int ni = 0; ni < 4; ++ni) {
      float* cp = C + (size_t)(row0 + mi * 16) * OUT_F + col0 + ni * 16;
#pragma unroll
      for (int r = 0; r < 4; ++r) cp[(size_t)r * OUT_F] = acc[mi][ni][r];
    }
}

extern "C" void kernel_launch(void* const* d_in, const int* in_sizes, int n_in,
                              void* d_out, int out_size, void* d_ws, size_t ws_size,
                              hipStream_t stream) {
  const float* x = (const float*)d_in[0];
  const float* wb = (const float*)d_in[1];
  const float* ws = (const float*)d_in[2];
  float* out = (float*)d_out;

  ushort_t* Apack = (ushort_t*)d_ws;                                    // 33.5 MB
  ushort_t* Wpack = (ushort_t*)((char*)d_ws + (size_t)BATCH * KP * 2);  // +4 MB

  prep_all<<<PREP_BLOCKS, 256, 0, stream>>>(x, wb, ws, Apack, Wpack);
  gemm_packed<<<dim3(OUT_F / 128, BATCH / 128), 256, 0, stream>>>(Apack, Wpack, out);
}

// Round 5
// 176.235 us; speedup vs baseline: 1.0782x; 1.0782x over previous
//
#include <hip/hip_runtime.h>
#include <hip/hip_bf16.h>

// KANLayer: out = x @ Wb^T + silu(x) @ sum_g(Ws)^T
// One packed bf16 GEMM, K=2048: A'=[x|silu(x)], W'=[Wb|sum_g Ws], out=A'@W'^T.
// R5: keep slot-major conflict-free LDS (R4: conflicts 6.3M -> 0) and dbuf,
//     but fix the window order: ds_read frags FIRST, then prefetch issue,
//     then MFMA, then ONE barrier. R4 issued loads before ds_reads -> compiler
//     inserted vmcnt(0) before the reads (LDS alias) = full latency exposed.

#define BATCH 8192
#define IN_F 1024
#define OUT_F 1024
#define KP 2048

typedef unsigned short ushort_t;
typedef __attribute__((ext_vector_type(8))) short short8;
typedef __attribute__((ext_vector_type(4))) float f32x4;

__device__ __forceinline__ ushort_t f2bf(float f) {
  union { float f; unsigned int u; } v;
  v.f = f;
  unsigned int u = v.u;
  u += 0x7fffu + ((u >> 16) & 1u);  // RNE
  return (ushort_t)(u >> 16);
}

__device__ __forceinline__ void async16(const ushort_t* g, ushort_t* l) {
  __builtin_amdgcn_global_load_lds(
      (const __attribute__((address_space(1))) void*)g,
      (__attribute__((address_space(3))) void*)l, 16, 0, 0);
}

// ---------------- merged prep (unchanged: ~traffic floor) -----------
#define PREP_A_BLOCKS 4096
#define PREP_S_BLOCKS 1024
#define PREP_B_BLOCKS 1024
#define PREP_BLOCKS (PREP_A_BLOCKS + PREP_S_BLOCKS + PREP_B_BLOCKS)

__global__ __launch_bounds__(256) void prep_all(
    const float* __restrict__ x, const float* __restrict__ Wb,
    const float* __restrict__ Ws, ushort_t* __restrict__ Apack,
    ushort_t* __restrict__ Wpack) {
  const int blk = blockIdx.x;
  const int t = threadIdx.x;

  if (blk < PREP_A_BLOCKS) {
    const int idx = blk * 256 + t;
    const int b = idx >> 7;
    const int i = (idx & 127) << 3;
    const float4 x0 = *(const float4*)(x + ((size_t)b << 10) + i);
    const float4 x1 = *(const float4*)(x + ((size_t)b << 10) + i + 4);
    float xv[8] = {x0.x, x0.y, x0.z, x0.w, x1.x, x1.y, x1.z, x1.w};
    ushort_t vb[8], vs[8];
#pragma unroll
    for (int j = 0; j < 8; ++j) {
      vb[j] = f2bf(xv[j]);
      vs[j] = f2bf(xv[j] / (1.0f + __expf(-xv[j])));
    }
    ushort_t* row = Apack + ((size_t)b << 11);
    *(short8*)(row + i) = *(short8*)vb;
    *(short8*)(row + IN_F + i) = *(short8*)vs;
  } else if (blk < PREP_A_BLOCKS + PREP_S_BLOCKS) {
    const int idx = (blk - PREP_A_BLOCKS) * 256 + t;
    const int o = idx >> 8;
    const int i0 = (idx & 255) << 2;
    ushort_t vs[4];
#pragma unroll
    for (int j = 0; j < 4; ++j) {
      const float4* p = (const float4*)(Ws + ((((size_t)o << 10) + i0 + j) << 3));
      const float4 a = p[0];
      const float4 b = p[1];
      vs[j] = f2bf(((a.x + a.y) + (a.z + a.w)) + ((b.x + b.y) + (b.z + b.w)));
    }
    *(ushort4*)(Wpack + ((size_t)o << 11) + IN_F + i0) = *(ushort4*)vs;
  } else {
    const int idx = (blk - PREP_A_BLOCKS - PREP_S_BLOCKS) * 256 + t;
    const int o = idx >> 8;
    const int c = (idx & 255) << 2;
    const float4 w = *(const float4*)(Wb + ((size_t)o << 10) + c);
    ushort4 v;
    v.x = f2bf(w.x); v.y = f2bf(w.y); v.z = f2bf(w.z); v.w = f2bf(w.w);
    *(ushort4*)(Wpack + ((size_t)o << 11) + c) = v;
  }
}

// ---------------- GEMM ----------------
// C[M][N] = A[M][K] @ W[N][K]^T. 128x128 tile, BK=32, 256 thr = 4 waves,
// wave tile 64x64 (4x4 frags of 16x16x32). Grid (8,64) = 512 blocks, 2/CU.
// Slot-major LDS buffer: [kslot 0..3][row 0..127][16B]; frag reads are 16B
// stride across 16 lanes -> 2 lanes/bank -> conflict-free (R4: measured 0).
// Window order per iter: barrier-drained buffer -> ds_read frags -> issue
// prefetch (other buffer) -> MFMA -> barrier (drain covered by MFMA phase).
__global__ __launch_bounds__(256) void gemm_packed(
    const ushort_t* __restrict__ A,  // [BATCH][KP]
    const ushort_t* __restrict__ W,  // [OUT_F][KP]
    float* __restrict__ C) {         // [BATCH][OUT_F]
  __shared__ ushort_t As[2 * 4096];  // 2 x 8 KB
  __shared__ ushort_t Bs[2 * 4096];

  const int t = threadIdx.x;
  const int flat = blockIdx.y * 8 + blockIdx.x;
  const int xcd = flat & 7;
  const int local = flat >> 3;           // 0..63
  const int nt = local >> 3;             // N-tile 0..7
  const int mt = xcd * 8 + (local & 7);  // M-tile 0..63 (XCD-local A slab)

  const int lane = t & 63;
  const int wave = t >> 6;
  const int wr = wave >> 1;
  const int wc = wave & 1;

  // staging: thread t covers (row=t&127, kslot=t>>7), 2 slot-pairs per tile
  const int srow = t & 127;
  const int sslot = t >> 7;
  const ushort_t* a_g = A + ((size_t)(mt * 128 + srow)) * KP + sslot * 8;
  const ushort_t* b_g = W + ((size_t)(nt * 128 + srow)) * KP + sslot * 8;
  const int t8 = t * 8;

  f32x4 acc[4][4];
#pragma unroll
  for (int mi = 0; mi < 4; ++mi)
#pragma unroll
    for (int ni = 0; ni < 4; ++ni) acc[mi][ni] = (f32x4){0.f, 0.f, 0.f, 0.f};

  const int arow = wr * 64 + (lane & 15);
  const int brow = wc * 64 + (lane & 15);
  const int rk = (lane >> 4) * 1024;  // kslot base (elems)

  // prologue: stage tile 0 into buffer 0
  async16(a_g, As + t8);
  async16(a_g + 16, As + 2048 + t8);
  async16(b_g, Bs + t8);
  async16(b_g + 16, Bs + 2048 + t8);
  __syncthreads();  // drain prologue

  int poff = 0;  // current buffer elem offset (0 or 4096)
  for (int k0 = 0; k0 < KP; k0 += 32) {
    // 1) fragment reads from current buffer (no outstanding vmem here)
    const ushort_t* ab = As + poff + rk;
    const ushort_t* bb = Bs + poff + rk;
    short8 af[4], bfr[4];
#pragma unroll
    for (int mi = 0; mi < 4; ++mi)
      af[mi] = *(const short8*)(ab + (arow + mi * 16) * 8);
#pragma unroll
    for (int ni = 0; ni < 4; ++ni)
      bfr[ni] = *(const short8*)(bb + (brow + ni * 16) * 8);

    __builtin_amdgcn_sched_barrier(0);  // keep ds_reads before prefetch issues

    // 2) prefetch next tile into the other buffer
    const int qoff = poff ^ 4096;
    if (k0 + 32 < KP) {
      async16(a_g + k0 + 32, As + qoff + t8);
      async16(a_g + k0 + 48, As + qoff + 2048 + t8);
      async16(b_g + k0 + 32, Bs + qoff + t8);
      async16(b_g + k0 + 48, Bs + qoff + 2048 + t8);
    }

    __builtin_amdgcn_sched_barrier(0);  // keep issues before MFMA phase

    // 3) compute: MFMA phase covers the prefetch flight time
#pragma unroll
    for (int mi = 0; mi < 4; ++mi)
#pragma unroll
      for (int ni = 0; ni < 4; ++ni)
        acc[mi][ni] = __builtin_amdgcn_mfma_f32_16x16x32_bf16(af[mi], bfr[ni], acc[mi][ni], 0, 0, 0);

    // 4) single barrier: drains prefetch + guards buffer swap
    __syncthreads();
    poff = qoff;
  }

  const int col0 = nt * 128 + wc * 64 + (lane & 15);
  const int row0 = mt * 128 + wr * 64 + ((lane >> 4) << 2);
#pragma unroll
  for (int mi = 0; mi < 4; ++mi)
#pragma unroll
    for (int ni = 0; ni < 4; ++ni) {
      float* cp = C + (size_t)(row0 + mi * 16) * OUT_F + col0 + ni * 16;
#pragma unroll
      for (int r = 0; r < 4; ++r) cp[(size_t)r * OUT_F] = acc[mi][ni][r];
    }
}

extern "C" void kernel_launch(void* const* d_in, const int* in_sizes, int n_in,
                              void* d_out, int out_size, void* d_ws, size_t ws_size,
                              hipStream_t stream) {
  const float* x = (const float*)d_in[0];
  const float* wb = (const float*)d_in[1];
  const float* ws = (const float*)d_in[2];
  float* out = (float*)d_out;

  ushort_t* Apack = (ushort_t*)d_ws;                                    // 33.5 MB
  ushort_t* Wpack = (ushort_t*)((char*)d_ws + (size_t)BATCH * KP * 2);  // +4 MB

  prep_all<<<PREP_BLOCKS, 256, 0, stream>>>(x, wb, ws, Apack, Wpack);
  gemm_packed<<<dim3(OUT_F / 128, BATCH / 128), 256, 0, stream>>>(Apack, Wpack, out);
}